// Round 6
// baseline (28867.795 us; speedup 1.0000x reference)
//
#include <hip/hip_runtime.h>
#include <cstdint>
#include <cstddef>

#define FLAG_RES  1
#define FLAG_GELU 2

__device__ __forceinline__ float gelu_exact(float x) {
    return 0.5f * x * (1.0f + erff(x * 0.70710678118654752f));
}

// ---------------------------------------------------------------------------
// Plain fp32 GEMM: C(M,N) = A(M,K) @ B(K,N) + bias, natural layouts.
// 64x64 tile, 256 threads, 4x4 outputs/thread. Rows k>=Kb of B read as 0.
// M%64==0, N%64==0, K%16==0.
// ---------------------------------------------------------------------------
__global__ __launch_bounds__(256) void gemm32(
    const float* __restrict__ A, const float* __restrict__ B,
    const float* __restrict__ bias, const float* __restrict__ resid,
    float* __restrict__ out, int M, int N, int K, int Kb, int flags)
{
    __shared__ float As[16][68];
    __shared__ float Bs[16][68];
    const int t = threadIdx.x;
    const int bm = blockIdx.y * 64;
    const int bn = blockIdx.x * 64;
    const int tm = (t >> 4) * 4;
    const int tn = (t & 15) * 4;

    float acc[4][4];
#pragma unroll
    for (int i = 0; i < 4; i++)
#pragma unroll
        for (int j = 0; j < 4; j++) acc[i][j] = 0.f;

    for (int k0 = 0; k0 < K; k0 += 16) {
#pragma unroll
        for (int p = 0; p < 4; p++) {
            const int m = (t >> 4) + p * 16;
            const int kk = t & 15;
            As[kk][m] = A[(size_t)(bm + m) * K + k0 + kk];
        }
#pragma unroll
        for (int p = 0; p < 4; p++) {
            const int kk = (t >> 6) + p * 4;
            const int n = t & 63;
            const int kg = k0 + kk;
            Bs[kk][n] = (kg < Kb) ? B[(size_t)kg * N + bn + n] : 0.f;
        }
        __syncthreads();
#pragma unroll
        for (int kk = 0; kk < 16; kk++) {
            const float4 av = *(const float4*)&As[kk][tm];
            const float4 bv = *(const float4*)&Bs[kk][tn];
            const float a[4] = {av.x, av.y, av.z, av.w};
            const float b[4] = {bv.x, bv.y, bv.z, bv.w};
#pragma unroll
            for (int i = 0; i < 4; i++)
#pragma unroll
                for (int j = 0; j < 4; j++)
                    acc[i][j] += a[i] * b[j];
        }
        __syncthreads();
    }

#pragma unroll
    for (int i = 0; i < 4; i++) {
        const int gm = bm + tm + i;
#pragma unroll
        for (int j = 0; j < 4; j++) {
            const int gn = bn + tn + j;
            float v = acc[i][j] + bias[gn];
            if (flags & FLAG_GELU) v = gelu_exact(v);
            const size_t off = (size_t)gm * N + gn;
            if (flags & FLAG_RES) v += resid[off];
            out[off] = v;
        }
    }
}

// ---------------------------------------------------------------------------
// Row LayerNorm over 512 cols, fp32 in/out. One wave per row, 4 rows/block.
// ---------------------------------------------------------------------------
__global__ __launch_bounds__(256) void ln_rows(
    const float* __restrict__ x, const float* __restrict__ w,
    const float* __restrict__ b, float* __restrict__ out)
{
    const int wid = threadIdx.x >> 6, lane = threadIdx.x & 63;
    const size_t row = (size_t)blockIdx.x * 4 + wid;
    const int c0 = lane * 8;
    const float* xr = x + row * 512 + c0;
    float4 v0 = *(const float4*)xr;
    float4 v1 = *(const float4*)(xr + 4);
    float xv[8] = {v0.x, v0.y, v0.z, v0.w, v1.x, v1.y, v1.z, v1.w};
    float s = 0.f, q = 0.f;
#pragma unroll
    for (int j = 0; j < 8; j++) { s += xv[j]; q += xv[j] * xv[j]; }
#pragma unroll
    for (int m = 32; m >= 1; m >>= 1) {
        s += __shfl_xor(s, m, 64);
        q += __shfl_xor(q, m, 64);
    }
    const float mean = s * (1.f / 512.f);
    const float rstd = rsqrtf(q * (1.f / 512.f) - mean * mean + 1e-5f);
    float o[8];
#pragma unroll
    for (int j = 0; j < 8; j++)
        o[j] = (xv[j] - mean) * rstd * w[c0 + j] + b[c0 + j];
    *(float4*)(out + row * 512 + c0) = make_float4(o[0], o[1], o[2], o[3]);
    *(float4*)(out + row * 512 + c0 + 4) = make_float4(o[4], o[5], o[6], o[7]);
}

// ---------------------------------------------------------------------------
// Attention: one wave per (b, head). 12x12 fp32 softmax in LDS.
// ---------------------------------------------------------------------------
__global__ __launch_bounds__(64) void attn_k(
    const float* __restrict__ qkv, float* __restrict__ o)
{
    const int b = blockIdx.x >> 3, hd = blockIdx.x & 7;
    const int lane = threadIdx.x;
    __shared__ float qs[12][65], ks[12][65], vs[12][65];
    __shared__ float att[12][16];
    const float* base = qkv + (size_t)b * (12 * 1536) + hd * 64 + lane;
#pragma unroll
    for (int r = 0; r < 12; r++) {
        qs[r][lane] = base[r * 1536];
        ks[r][lane] = base[r * 1536 + 512];
        vs[r][lane] = base[r * 1536 + 1024];
    }
    __syncthreads();
#pragma unroll
    for (int i = 0; i < 3; i++) {
        const int p = lane + i * 64;
        if (p < 144) {
            const int qi = p / 12, kj = p - qi * 12;
            float d = 0.f;
            for (int e = 0; e < 64; e++) d += qs[qi][e] * ks[kj][e];
            att[qi][kj] = d * 0.125f;
        }
    }
    __syncthreads();
    if (lane < 12) {
        float mx = att[lane][0];
#pragma unroll
        for (int j = 1; j < 12; j++) mx = fmaxf(mx, att[lane][j]);
        float ev[12], ssum = 0.f;
#pragma unroll
        for (int j = 0; j < 12; j++) { ev[j] = expf(att[lane][j] - mx); ssum += ev[j]; }
        const float inv = 1.f / ssum;
#pragma unroll
        for (int j = 0; j < 12; j++) att[lane][j] = ev[j] * inv;
    }
    __syncthreads();
    float* ob = o + (size_t)b * (12 * 512) + hd * 64 + lane;
#pragma unroll
    for (int qi = 0; qi < 12; qi++) {
        float s = 0.f;
#pragma unroll
        for (int j = 0; j < 12; j++) s += att[qi][j] * vs[j][lane];
        ob[qi * 512] = s;
    }
}

// ---------------------------------------------------------------------------
// Factors: one thread per batch row; serial T=96 scan. CH batches per chunk.
// ---------------------------------------------------------------------------
__global__ __launch_bounds__(64) void factors_k(
    const float* __restrict__ x, float* __restrict__ raw, float* __restrict__ stats,
    int CH)
{
    const int tid = threadIdx.x;
    const int b = blockIdx.x * 64 + tid;
    if (b >= CH) return;
    __shared__ float cl[96][64];
    __shared__ float vl[96][64];
    const float* xb = x + (size_t)b * 480;
    for (int t = 0; t < 96; t++) {
        cl[t][tid] = xb[t * 5 + 3];
        vl[t][tid] = xb[t * 5 + 4];
    }
    float e12 = cl[0][tid], e26 = e12;
    float ag = 0.f, al = 0.f;
    float s1c = 0.f, s2c = 0.f, s1v = 0.f;
    float sum[11], ssq[11];
#pragma unroll
    for (int f = 0; f < 11; f++) { sum[f] = 0.f; ssq[f] = 0.f; }
    const float a12 = 2.f / 13.f, a26 = 2.f / 27.f, a14 = 1.f / 14.f;
    for (int t = 0; t < 96; t++) {
        const float c = cl[t][tid];
        const float vraw = vl[t][tid];
        const float sv = vraw > 0.f ? vraw : 1.f;
        if (t > 0) {
            e12 = a12 * c + (1.f - a12) * e12;
            e26 = a26 * c + (1.f - a26) * e26;
        }
        const float macd = e12 - e26;
        const float cprev = t > 0 ? cl[t - 1][tid] : 0.f;
        const float delta = t > 0 ? c - cprev : 0.f;
        const float gain = fmaxf(delta, 0.f);
        const float loss = fmaxf(-delta, 0.f);
        if (t > 0) {
            ag = a14 * gain + (1.f - a14) * ag;
            al = a14 * loss + (1.f - a14) * al;
        }
        const float rs = ag / (al + 1e-10f);
        const float rsi = (100.f - 100.f / (1.f + rs)) * 0.01f;
        s1c += c; s2c += c * c; s1v += sv;
        if (t >= 20) {
            const float co = cl[t - 20][tid];
            const float vo = vl[t - 20][tid];
            const float svo = vo > 0.f ? vo : 1.f;
            s1c -= co; s2c -= co * co; s1v -= svo;
        }
        float bb = 0.f, vmr = 1.f;
        if (t >= 19) {
            const float mean = s1c * 0.05f;
            const float sq = s2c * 0.05f;
            const float sd = sqrtf(fmaxf(sq - mean * mean, 0.f));
            bb = 4.f * sd / (mean + 1e-8f);
            vmr = sv / (s1v * 0.05f + 1e-8f);
        }
        float lr = 0.f, lv = 0.f;
        if (t > 0) {
            lr = logf(fmaxf(c, 1e-8f) / fmaxf(cprev, 1e-8f));
            const float vprev = vl[t - 1][tid];
            const float svp = vprev > 0.f ? vprev : 1.f;
            lv = logf(sv / (svp + 1e-8f));
        }
        float fv[11];
        fv[0] = xb[t * 5 + 0];
        fv[1] = xb[t * 5 + 1];
        fv[2] = xb[t * 5 + 2];
        fv[3] = c;
        fv[4] = vraw;
        fv[5] = isfinite(macd) ? macd : 0.f;
        fv[6] = isfinite(rsi) ? rsi : 0.f;
        fv[7] = isfinite(bb) ? bb : 0.f;
        fv[8] = isfinite(lr) ? lr : 0.f;
        fv[9] = isfinite(lv) ? lv : 0.f;
        fv[10] = isfinite(vmr) ? vmr : 0.f;
        float* rp = raw + ((size_t)b * 96 + t) * 11;
#pragma unroll
        for (int f = 0; f < 11; f++) {
            rp[f] = fv[f];
            sum[f] += fv[f];
            ssq[f] += fv[f] * fv[f];
        }
    }
#pragma unroll
    for (int f = 0; f < 11; f++) {
        const float m = sum[f] * (1.f / 96.f);
        const float var = ssq[f] * (1.f / 96.f) - m * m;
        stats[(b * 11 + f) * 2] = m;
        stats[(b * 11 + f) * 2 + 1] = rsqrtf(var + 1e-5f);
    }
}

// ---------------------------------------------------------------------------
// Normalize feats -> (CH*12, 96) fp32 patch rows (cols 88..95 zero).
// ---------------------------------------------------------------------------
__global__ __launch_bounds__(256) void featnorm_k(
    const float* __restrict__ raw, const float* __restrict__ stats,
    const float* __restrict__ in_w, const float* __restrict__ in_b,
    float* __restrict__ out)
{
    const int idx = blockIdx.x * 256 + threadIdx.x;
    const int row = idx / 96;
    const int col = idx - row * 96;
    float val = 0.f;
    if (col < 88) {
        const int bq = row / 12;
        const int p = row - bq * 12;
        const int tsub = col / 11;
        const int f = col - tsub * 11;
        const int t = p * 8 + tsub;
        const float fvv = raw[((size_t)bq * 96 + t) * 11 + f];
        const float m = stats[(bq * 11 + f) * 2];
        const float r = stats[(bq * 11 + f) * 2 + 1];
        val = (fvv - m) * r * in_w[f] + in_b[f];
    }
    out[idx] = val;
}

// ---------------------------------------------------------------------------
// Final tiny GEMM: (CH x 128) @ (128 x 3) + bias -> fp32 out.
// ---------------------------------------------------------------------------
__global__ __launch_bounds__(256) void cls3_k(
    const float* __restrict__ f2, const float* __restrict__ w3,
    const float* __restrict__ b3, float* __restrict__ out, int CH)
{
    const int bq = blockIdx.x * 256 + threadIdx.x;
    if (bq >= CH) return;
    float a0 = b3[0], a1 = b3[1], a2 = b3[2];
    const float* fr = f2 + (size_t)bq * 128;
    for (int k = 0; k < 128; k++) {
        const float xv = fr[k];
        a0 += xv * w3[k * 3];
        a1 += xv * w3[k * 3 + 1];
        a2 += xv * w3[k * 3 + 2];
    }
    out[bq * 3] = a0;
    out[bq * 3 + 1] = a1;
    out[bq * 3 + 2] = a2;
}

// ---------------------------------------------------------------------------
extern "C" void kernel_launch(void* const* d_in, const int* in_sizes, int n_in,
                              void* d_out, int out_size, void* d_ws, size_t ws_size,
                              hipStream_t stream)
{
    // ---- contract verification: documented dict order, else sorted-name ----
    static const int EXP[23] = {1966080, 11, 11, 45056, 512, 2048, 2048,
        3145728, 6144, 1048576, 2048, 2048, 2048, 4194304, 8192, 4194304, 2048,
        3145728, 512, 65536, 128, 384, 3};
    // sorted names: cls_b1,cls_b2,cls_b3,cls_w1,cls_w2,cls_w3,in_b,in_w,
    //   ln1_b,ln1_w,ln2_b,ln2_w,mlp_b1,mlp_b2,mlp_w1,mlp_w2,out_b,out_w,
    //   pe_b,pe_w,qkv_b,qkv_w,x  -> dict indices:
    static const int S2D[23] = {18, 20, 22, 17, 19, 21, 2, 1, 6, 5, 12, 11,
        14, 16, 13, 15, 10, 9, 4, 3, 8, 7, 0};
    const void* in[23];
    if (n_in != 23 || out_size != 12288) return;   // d_out stays 0 -> signal
    bool ok = true;
    for (int i = 0; i < 23; i++) ok = ok && (in_sizes[i] == EXP[i]);
    if (ok) {
        for (int i = 0; i < 23; i++) in[i] = d_in[i];
    } else {
        bool ok2 = true;
        for (int s = 0; s < 23; s++) ok2 = ok2 && (in_sizes[s] == EXP[S2D[s]]);
        if (!ok2) return;                          // d_out stays 0 -> signal
        for (int s = 0; s < 23; s++) in[S2D[s]] = d_in[s];
    }
    const float* x      = (const float*)in[0];
    const float* in_w   = (const float*)in[1];
    const float* in_b   = (const float*)in[2];
    const float* pe_w   = (const float*)in[3];
    const float* pe_b   = (const float*)in[4];
    const float* ln1_w  = (const float*)in[5];
    const float* ln1_b  = (const float*)in[6];
    const float* qkv_w  = (const float*)in[7];
    const float* qkv_b  = (const float*)in[8];
    const float* out_w  = (const float*)in[9];
    const float* out_b  = (const float*)in[10];
    const float* ln2_w  = (const float*)in[11];
    const float* ln2_b  = (const float*)in[12];
    const float* mlp_w1 = (const float*)in[13];
    const float* mlp_b1 = (const float*)in[14];
    const float* mlp_w2 = (const float*)in[15];
    const float* mlp_b2 = (const float*)in[16];
    const float* cls_w1 = (const float*)in[17];
    const float* cls_b1 = (const float*)in[18];
    const float* cls_w2 = (const float*)in[19];
    const float* cls_b2 = (const float*)in[20];
    const float* cls_w3 = (const float*)in[21];
    const float* cls_b3 = (const float*)in[22];

    // ---- ws-adaptive chunk size: CH batches/chunk, 158936 B per batch ----
    const size_t per = 158936;
    int CH = 512;
    while (CH > 64 && (size_t)CH * per + 1024 > ws_size) CH >>= 1;
    const int nch = 4096 / CH;
    const int M = CH * 12;

    char* ws = (char*)d_ws;
    size_t off = 0;
    float* h32   = (float*)(ws + off); off += (size_t)M * 512 * 4;
    float* nbuf  = (float*)(ws + off); off += (size_t)M * 512 * 4;
    float* big   = (float*)(ws + off); off += (size_t)M * 2048 * 4;
    float* feats = (float*)(ws + off); off += (size_t)M * 96 * 4;
    float* raw   = (float*)(ws + off); off += (size_t)CH * 96 * 11 * 4;
    float* stats = (float*)(ws + off); off += (size_t)CH * 11 * 2 * 4;
    float* f1    = (float*)(ws + off); off += (size_t)CH * 512 * 4;
    float* f2    = (float*)(ws + off); off += (size_t)CH * 128 * 4;

    for (int c = 0; c < nch; c++) {
        const float* xc = x + (size_t)c * CH * 480;
        factors_k<<<(CH + 63) / 64, 64, 0, stream>>>(xc, raw, stats, CH);
        featnorm_k<<<(M * 96) / 256, 256, 0, stream>>>(raw, stats, in_w, in_b, feats);
        gemm32<<<dim3(8, M / 64), 256, 0, stream>>>(
            feats, pe_w, pe_b, nullptr, h32, M, 512, 96, 88, 0);

        for (int i = 0; i < 4; i++) {
            ln_rows<<<M / 4, 256, 0, stream>>>(h32, ln1_w + i * 512, ln1_b + i * 512, nbuf);
            gemm32<<<dim3(24, M / 64), 256, 0, stream>>>(
                nbuf, qkv_w + (size_t)i * 512 * 1536, qkv_b + i * 1536,
                nullptr, big, M, 1536, 512, 512, 0);
            attn_k<<<CH * 8, 64, 0, stream>>>(big, nbuf);
            gemm32<<<dim3(8, M / 64), 256, 0, stream>>>(
                nbuf, out_w + (size_t)i * 512 * 512, out_b + i * 512,
                h32, h32, M, 512, 512, 512, FLAG_RES);
            ln_rows<<<M / 4, 256, 0, stream>>>(h32, ln2_w + i * 512, ln2_b + i * 512, nbuf);
            gemm32<<<dim3(32, M / 64), 256, 0, stream>>>(
                nbuf, mlp_w1 + (size_t)i * 512 * 2048, mlp_b1 + i * 2048,
                nullptr, big, M, 2048, 512, 512, FLAG_GELU);
            gemm32<<<dim3(8, M / 64), 256, 0, stream>>>(
                big, mlp_w2 + (size_t)i * 2048 * 512, mlp_b2 + i * 512,
                h32, h32, M, 512, 2048, 2048, FLAG_RES);
        }

        // classifier: h32 viewed as (CH, 6144)
        gemm32<<<dim3(8, CH / 64), 256, 0, stream>>>(
            h32, cls_w1, cls_b1, nullptr, f1, CH, 512, 6144, 6144, FLAG_GELU);
        gemm32<<<dim3(2, CH / 64), 256, 0, stream>>>(
            f1, cls_w2, cls_b2, nullptr, f2, CH, 128, 512, 512, FLAG_GELU);
        cls3_k<<<(CH + 255) / 256, 256, 0, stream>>>(
            f2, cls_w3, cls_b3, (float*)d_out + (size_t)c * CH * 3, CH);
    }
}

// Round 7
// 4809.702 us; speedup vs baseline: 6.0020x; 6.0020x over previous
//
#include <hip/hip_runtime.h>
#include <cstdint>
#include <cstddef>

typedef _Float16 half8 __attribute__((ext_vector_type(8)));
typedef float floatx4 __attribute__((ext_vector_type(4)));

#define FLAG_RES  1
#define FLAG_GELU 2
#define FLAG_W32  4
#define FLAG_W16  8

__device__ __forceinline__ float gelu_exact(float x) {
    return 0.5f * x * (1.0f + erff(x * 0.70710678118654752f));
}

// ---------------------------------------------------------------------------
// GEMM: C(MxN) = A(MxK, f16 row-major) @ Bt(NxK, f16 row-major)^T + bias(fp32)
// 128x128 tile, BK=32, 256 threads (4 waves, 2x2 of 64x64), m97 structure:
// global_load_lds width=16 staging, ds_read_b128 fragments, fp32 accum.
// Requires M%128==0, N%128==0, K%32==0.
// ---------------------------------------------------------------------------
__global__ __launch_bounds__(256, 2) void gemm_f16(
    const _Float16* __restrict__ A, const _Float16* __restrict__ Bt,
    const float* __restrict__ bias, const float* __restrict__ resid,
    float* __restrict__ out32, _Float16* __restrict__ out16,
    int M, int N, int K, int flags)
{
    __shared__ _Float16 As[128 * 32];
    __shared__ _Float16 Bs[128 * 32];
    const int tid = threadIdx.x;
    const int wid = tid >> 6;
    const int lane = tid & 63;
    const int bm = blockIdx.y * 128;
    const int bn = blockIdx.x * 128;
    const int wr = wid >> 1, wc = wid & 1;
    const int lane15 = lane & 15, quad = lane >> 4;

    floatx4 acc[4][4];
#pragma unroll
    for (int i = 0; i < 4; i++)
#pragma unroll
        for (int j = 0; j < 4; j++)
            acc[i][j] = floatx4{0.f, 0.f, 0.f, 0.f};

    // staging: lane l covers row (base + l/4), cols (l%4)*8..+7 -> LDS + l*16B
    const int r4 = lane >> 2;
    const int c8 = (lane & 3) << 3;
    const _Float16* Ab = A + ((size_t)bm + wid * 32 + r4) * K + c8;
    const _Float16* Bb = Bt + ((size_t)bn + wid * 32 + r4) * K + c8;
    _Float16* lA = &As[(wid * 32) * 32];
    _Float16* lB = &Bs[(wid * 32) * 32];
    const size_t row16 = (size_t)16 * K;

    for (int k0 = 0; k0 < K; k0 += 32) {
        __builtin_amdgcn_global_load_lds(
            (const __attribute__((address_space(1))) void*)(Ab + k0),
            (__attribute__((address_space(3))) void*)lA, 16, 0, 0);
        __builtin_amdgcn_global_load_lds(
            (const __attribute__((address_space(1))) void*)(Ab + row16 + k0),
            (__attribute__((address_space(3))) void*)(lA + 16 * 32), 16, 0, 0);
        __builtin_amdgcn_global_load_lds(
            (const __attribute__((address_space(1))) void*)(Bb + k0),
            (__attribute__((address_space(3))) void*)lB, 16, 0, 0);
        __builtin_amdgcn_global_load_lds(
            (const __attribute__((address_space(1))) void*)(Bb + row16 + k0),
            (__attribute__((address_space(3))) void*)(lB + 16 * 32), 16, 0, 0);
        __syncthreads();

        half8 af[4], bf[4];
#pragma unroll
        for (int mi = 0; mi < 4; mi++)
            af[mi] = *(const half8*)&As[(wr * 64 + mi * 16 + lane15) * 32 + quad * 8];
#pragma unroll
        for (int ni = 0; ni < 4; ni++)
            bf[ni] = *(const half8*)&Bs[(wc * 64 + ni * 16 + lane15) * 32 + quad * 8];
#pragma unroll
        for (int mi = 0; mi < 4; mi++)
#pragma unroll
            for (int ni = 0; ni < 4; ni++)
                acc[mi][ni] = __builtin_amdgcn_mfma_f32_16x16x32_f16(
                    af[mi], bf[ni], acc[mi][ni], 0, 0, 0);
        __syncthreads();
    }

    // epilogue: C/D layout col = lane&15, row = quad*4 + reg
#pragma unroll
    for (int mi = 0; mi < 4; mi++) {
        const int gmb = bm + wr * 64 + mi * 16 + quad * 4;
#pragma unroll
        for (int ni = 0; ni < 4; ni++) {
            const int gn = bn + wc * 64 + ni * 16 + lane15;
            const float bv = bias[gn];
#pragma unroll
            for (int r = 0; r < 4; r++) {
                float v = acc[mi][ni][r] + bv;
                if (flags & FLAG_GELU) v = gelu_exact(v);
                const size_t off = (size_t)(gmb + r) * N + gn;
                if (flags & FLAG_RES) v += resid[off];
                if (flags & FLAG_W32) out32[off] = v;
                if (flags & FLAG_W16) out16[off] = (_Float16)v;
            }
        }
    }
}

// ---------------------------------------------------------------------------
// Row LayerNorm over 512 cols: fp32 in, fp32 params, f16 out. One wave/row.
// ---------------------------------------------------------------------------
__global__ __launch_bounds__(256) void ln_rows(
    const float* __restrict__ x, const float* __restrict__ w,
    const float* __restrict__ b, _Float16* __restrict__ out)
{
    const int wid = threadIdx.x >> 6, lane = threadIdx.x & 63;
    const size_t row = (size_t)blockIdx.x * 4 + wid;
    const int c0 = lane * 8;
    const float* xr = x + row * 512 + c0;
    float4 v0 = *(const float4*)xr;
    float4 v1 = *(const float4*)(xr + 4);
    float xv[8] = {v0.x, v0.y, v0.z, v0.w, v1.x, v1.y, v1.z, v1.w};
    float s = 0.f, q = 0.f;
#pragma unroll
    for (int j = 0; j < 8; j++) { s += xv[j]; q += xv[j] * xv[j]; }
#pragma unroll
    for (int m = 32; m >= 1; m >>= 1) {
        s += __shfl_xor(s, m, 64);
        q += __shfl_xor(q, m, 64);
    }
    const float mean = s * (1.f / 512.f);
    const float rstd = rsqrtf(q * (1.f / 512.f) - mean * mean + 1e-5f);
    half8 o;
#pragma unroll
    for (int j = 0; j < 8; j++)
        o[j] = (_Float16)((xv[j] - mean) * rstd * w[c0 + j] + b[c0 + j]);
    *(half8*)&out[row * 512 + c0] = o;
}

// ---------------------------------------------------------------------------
// Attention: one wave per (b, head). 12x12 fp32 softmax in LDS. f16 in/out.
// qkv rows (1536): [q|k|v], head offset hd*64.
// ---------------------------------------------------------------------------
__global__ __launch_bounds__(64) void attn_k(
    const _Float16* __restrict__ qkv, _Float16* __restrict__ o)
{
    const int b = blockIdx.x >> 3, hd = blockIdx.x & 7;
    const int lane = threadIdx.x;
    __shared__ float qs[12][65], ks[12][65], vs[12][65];
    __shared__ float att[12][16];
    const _Float16* base = qkv + (size_t)b * (12 * 1536) + hd * 64 + lane;
#pragma unroll
    for (int r = 0; r < 12; r++) {
        qs[r][lane] = (float)base[r * 1536];
        ks[r][lane] = (float)base[r * 1536 + 512];
        vs[r][lane] = (float)base[r * 1536 + 1024];
    }
    __syncthreads();
#pragma unroll
    for (int i = 0; i < 3; i++) {
        const int p = lane + i * 64;
        if (p < 144) {
            const int qi = p / 12, kj = p - qi * 12;
            float d = 0.f;
            for (int e = 0; e < 64; e++) d += qs[qi][e] * ks[kj][e];
            att[qi][kj] = d * 0.125f;   // 1/sqrt(64)
        }
    }
    __syncthreads();
    if (lane < 12) {
        float mx = att[lane][0];
#pragma unroll
        for (int j = 1; j < 12; j++) mx = fmaxf(mx, att[lane][j]);
        float ev[12], ssum = 0.f;
#pragma unroll
        for (int j = 0; j < 12; j++) { ev[j] = expf(att[lane][j] - mx); ssum += ev[j]; }
        const float inv = 1.f / ssum;
#pragma unroll
        for (int j = 0; j < 12; j++) att[lane][j] = ev[j] * inv;
    }
    __syncthreads();
    _Float16* ob = o + (size_t)b * (12 * 512) + hd * 64 + lane;
#pragma unroll
    for (int qi = 0; qi < 12; qi++) {
        float s = 0.f;
#pragma unroll
        for (int j = 0; j < 12; j++) s += att[qi][j] * vs[j][lane];
        ob[qi * 512] = (_Float16)s;
    }
}

// ---------------------------------------------------------------------------
// Factors: one thread per batch row; serial T=96 scan. CH batches per chunk.
// ---------------------------------------------------------------------------
__global__ __launch_bounds__(64) void factors_k(
    const float* __restrict__ x, float* __restrict__ raw, float* __restrict__ stats,
    int CH)
{
    const int tid = threadIdx.x;
    const int b = blockIdx.x * 64 + tid;
    if (b >= CH) return;
    __shared__ float cl[96][64];
    __shared__ float vl[96][64];
    const float* xb = x + (size_t)b * 480;
    for (int t = 0; t < 96; t++) {
        cl[t][tid] = xb[t * 5 + 3];
        vl[t][tid] = xb[t * 5 + 4];
    }
    float e12 = cl[0][tid], e26 = e12;
    float ag = 0.f, al = 0.f;
    float s1c = 0.f, s2c = 0.f, s1v = 0.f;
    float sum[11], ssq[11];
#pragma unroll
    for (int f = 0; f < 11; f++) { sum[f] = 0.f; ssq[f] = 0.f; }
    const float a12 = 2.f / 13.f, a26 = 2.f / 27.f, a14 = 1.f / 14.f;
    for (int t = 0; t < 96; t++) {
        const float c = cl[t][tid];
        const float vraw = vl[t][tid];
        const float sv = vraw > 0.f ? vraw : 1.f;
        if (t > 0) {
            e12 = a12 * c + (1.f - a12) * e12;
            e26 = a26 * c + (1.f - a26) * e26;
        }
        const float macd = e12 - e26;
        const float cprev = t > 0 ? cl[t - 1][tid] : 0.f;
        const float delta = t > 0 ? c - cprev : 0.f;
        const float gain = fmaxf(delta, 0.f);
        const float loss = fmaxf(-delta, 0.f);
        if (t > 0) {
            ag = a14 * gain + (1.f - a14) * ag;
            al = a14 * loss + (1.f - a14) * al;
        }
        const float rs = ag / (al + 1e-10f);
        const float rsi = (100.f - 100.f / (1.f + rs)) * 0.01f;
        s1c += c; s2c += c * c; s1v += sv;
        if (t >= 20) {
            const float co = cl[t - 20][tid];
            const float vo = vl[t - 20][tid];
            const float svo = vo > 0.f ? vo : 1.f;
            s1c -= co; s2c -= co * co; s1v -= svo;
        }
        float bb = 0.f, vmr = 1.f;
        if (t >= 19) {
            const float mean = s1c * 0.05f;
            const float sq = s2c * 0.05f;
            const float sd = sqrtf(fmaxf(sq - mean * mean, 0.f));
            bb = 4.f * sd / (mean + 1e-8f);
            vmr = sv / (s1v * 0.05f + 1e-8f);
        }
        float lr = 0.f, lv = 0.f;
        if (t > 0) {
            lr = logf(fmaxf(c, 1e-8f) / fmaxf(cprev, 1e-8f));
            const float vprev = vl[t - 1][tid];
            const float svp = vprev > 0.f ? vprev : 1.f;
            lv = logf(sv / (svp + 1e-8f));
        }
        float fv[11];
        fv[0] = xb[t * 5 + 0];
        fv[1] = xb[t * 5 + 1];
        fv[2] = xb[t * 5 + 2];
        fv[3] = c;
        fv[4] = vraw;
        fv[5] = isfinite(macd) ? macd : 0.f;
        fv[6] = isfinite(rsi) ? rsi : 0.f;
        fv[7] = isfinite(bb) ? bb : 0.f;
        fv[8] = isfinite(lr) ? lr : 0.f;
        fv[9] = isfinite(lv) ? lv : 0.f;
        fv[10] = isfinite(vmr) ? vmr : 0.f;
        float* rp = raw + ((size_t)b * 96 + t) * 11;
#pragma unroll
        for (int f = 0; f < 11; f++) {
            rp[f] = fv[f];
            sum[f] += fv[f];
            ssq[f] += fv[f] * fv[f];
        }
    }
#pragma unroll
    for (int f = 0; f < 11; f++) {
        const float m = sum[f] * (1.f / 96.f);
        const float var = ssq[f] * (1.f / 96.f) - m * m;
        stats[(b * 11 + f) * 2] = m;
        stats[(b * 11 + f) * 2 + 1] = rsqrtf(var + 1e-5f);
    }
}

// ---------------------------------------------------------------------------
// Normalize feats -> (CH*12, 96) f16 patch rows (cols 88..95 zero pad).
// ---------------------------------------------------------------------------
__global__ __launch_bounds__(256) void featnorm_k(
    const float* __restrict__ raw, const float* __restrict__ stats,
    const float* __restrict__ in_w, const float* __restrict__ in_b,
    _Float16* __restrict__ out)
{
    const int idx = blockIdx.x * 256 + threadIdx.x;
    const int row = idx / 96;
    const int col = idx - row * 96;
    float val = 0.f;
    if (col < 88) {
        const int bq = row / 12;
        const int p = row - bq * 12;
        const int tsub = col / 11;
        const int f = col - tsub * 11;
        const int t = p * 8 + tsub;
        const float fvv = raw[((size_t)bq * 96 + t) * 11 + f];
        const float m = stats[(bq * 11 + f) * 2];
        const float r = stats[(bq * 11 + f) * 2 + 1];
        val = (fvv - m) * r * in_w[f] + in_b[f];
    }
    out[idx] = (_Float16)val;
}

// ---------------------------------------------------------------------------
// Tiled transpose + cast: W (K x N) fp32 -> Wt (N x Kpad) f16, zero-pad.
// grid (N/32, Kpad/32), block (32,8).
// ---------------------------------------------------------------------------
__global__ __launch_bounds__(256) void tr_k(
    const float* __restrict__ W, _Float16* __restrict__ Wt,
    int K, int N, int Kpad)
{
    __shared__ _Float16 t[32][33];
    const int n0 = blockIdx.x * 32, k0 = blockIdx.y * 32;
#pragma unroll
    for (int j = 0; j < 4; j++) {
        const int k = k0 + threadIdx.y + j * 8;
        t[threadIdx.y + j * 8][threadIdx.x] =
            (k < K) ? (_Float16)W[(size_t)k * N + n0 + threadIdx.x] : (_Float16)0.f;
    }
    __syncthreads();
#pragma unroll
    for (int j = 0; j < 4; j++) {
        const int n = n0 + threadIdx.y + j * 8;
        Wt[(size_t)n * Kpad + k0 + threadIdx.x] = t[threadIdx.x][threadIdx.y + j * 8];
    }
}

// ---------------------------------------------------------------------------
// Final tiny GEMM: (CH x 128 f16) @ (128 x 3) + bias -> fp32 out.
// ---------------------------------------------------------------------------
__global__ __launch_bounds__(256) void cls3_k(
    const _Float16* __restrict__ f2, const float* __restrict__ w3,
    const float* __restrict__ b3, float* __restrict__ out, int CH)
{
    const int bq = blockIdx.x * 256 + threadIdx.x;
    if (bq >= CH) return;
    float a0 = b3[0], a1 = b3[1], a2 = b3[2];
    const _Float16* fr = f2 + (size_t)bq * 128;
    for (int k = 0; k < 128; k++) {
        const float xv = (float)fr[k];
        a0 += xv * w3[k * 3];
        a1 += xv * w3[k * 3 + 1];
        a2 += xv * w3[k * 3 + 2];
    }
    out[bq * 3] = a0;
    out[bq * 3 + 1] = a1;
    out[bq * 3 + 2] = a2;
}

// ---------------------------------------------------------------------------
extern "C" void kernel_launch(void* const* d_in, const int* in_sizes, int n_in,
                              void* d_out, int out_size, void* d_ws, size_t ws_size,
                              hipStream_t stream)
{
    // ---- contract verification (passed in R6): dict order, else sorted ----
    static const int EXP[23] = {1966080, 11, 11, 45056, 512, 2048, 2048,
        3145728, 6144, 1048576, 2048, 2048, 2048, 4194304, 8192, 4194304, 2048,
        3145728, 512, 65536, 128, 384, 3};
    static const int S2D[23] = {18, 20, 22, 17, 19, 21, 2, 1, 6, 5, 12, 11,
        14, 16, 13, 15, 10, 9, 4, 3, 8, 7, 0};
    const void* in[23];
    if (n_in != 23 || out_size != 12288) return;
    bool ok = true;
    for (int i = 0; i < 23; i++) ok = ok && (in_sizes[i] == EXP[i]);
    if (ok) {
        for (int i = 0; i < 23; i++) in[i] = d_in[i];
    } else {
        bool ok2 = true;
        for (int s = 0; s < 23; s++) ok2 = ok2 && (in_sizes[s] == EXP[S2D[s]]);
        if (!ok2) return;
        for (int s = 0; s < 23; s++) in[S2D[s]] = d_in[s];
    }
    const float* x      = (const float*)in[0];
    const float* in_w   = (const float*)in[1];
    const float* in_b   = (const float*)in[2];
    const float* pe_w   = (const float*)in[3];
    const float* pe_b   = (const float*)in[4];
    const float* ln1_w  = (const float*)in[5];
    const float* ln1_b  = (const float*)in[6];
    const float* qkv_w  = (const float*)in[7];
    const float* qkv_b  = (const float*)in[8];
    const float* out_w  = (const float*)in[9];
    const float* out_b  = (const float*)in[10];
    const float* ln2_w  = (const float*)in[11];
    const float* ln2_b  = (const float*)in[12];
    const float* mlp_w1 = (const float*)in[13];
    const float* mlp_b1 = (const float*)in[14];
    const float* mlp_w2 = (const float*)in[15];
    const float* mlp_b2 = (const float*)in[16];
    const float* cls_w1 = (const float*)in[17];
    const float* cls_b1 = (const float*)in[18];
    const float* cls_w2 = (const float*)in[19];
    const float* cls_b2 = (const float*)in[20];
    const float* cls_w3 = (const float*)in[21];
    const float* cls_b3 = (const float*)in[22];

    // ---- f16 weight arena (fixed, ~31.7 MB) + per-chunk buffers ----
    char* ws = (char*)d_ws;
    size_t off = 0;
    _Float16* wt_pe  = (_Float16*)(ws + off); off += (size_t)512 * 96 * 2;
    _Float16* wt_qkv = (_Float16*)(ws + off); off += (size_t)4 * 1536 * 512 * 2;
    _Float16* wt_out = (_Float16*)(ws + off); off += (size_t)4 * 512 * 512 * 2;
    _Float16* wt_m1  = (_Float16*)(ws + off); off += (size_t)4 * 2048 * 512 * 2;
    _Float16* wt_m2  = (_Float16*)(ws + off); off += (size_t)4 * 512 * 2048 * 2;
    _Float16* wt_c1  = (_Float16*)(ws + off); off += (size_t)512 * 6144 * 2;
    _Float16* wt_c2  = (_Float16*)(ws + off); off += (size_t)128 * 512 * 2;
    const size_t wbytes = off;

    // adaptive chunk: per-batch buffer bytes =
    //   h32 24576 + abuf 12288 + bbuf 49152 + raw 4224 + stats 88 = 90328
    const size_t per = 90328 + 64;
    int CH = 1024;                 // 125.5 MB total, R3-proven to fit
    while (CH > 128 && wbytes + (size_t)CH * per > ws_size) CH >>= 1;
    const int nch = 4096 / CH;
    const int M = CH * 12;

    float*    h32  = (float*)(ws + off);    off += (size_t)M * 512 * 4;
    _Float16* abuf = (_Float16*)(ws + off); off += (size_t)M * 512 * 2;
    _Float16* bbuf = (_Float16*)(ws + off); off += (size_t)M * 2048 * 2;
    float*    raw  = (float*)(ws + off);    off += (size_t)CH * 96 * 11 * 4;
    float*    stats= (float*)(ws + off);    off += (size_t)CH * 11 * 2 * 4;

    _Float16* feats = bbuf;                 // dead after pe GEMM
    _Float16* f1 = (_Float16*)raw;          // classifier temps (raw dead then)
    _Float16* f2 = f1 + (size_t)CH * 512;

    // ---- weight prep: fp32 (K,N) -> f16 (N,Kpad) transposed (once) ----
    tr_k<<<dim3(16, 3),  dim3(32, 8), 0, stream>>>(pe_w, wt_pe, 88, 512, 96);
    for (int i = 0; i < 4; i++) {
        tr_k<<<dim3(48, 16), dim3(32, 8), 0, stream>>>(
            qkv_w + (size_t)i * 512 * 1536, wt_qkv + (size_t)i * 1536 * 512, 512, 1536, 512);
        tr_k<<<dim3(16, 16), dim3(32, 8), 0, stream>>>(
            out_w + (size_t)i * 512 * 512, wt_out + (size_t)i * 512 * 512, 512, 512, 512);
        tr_k<<<dim3(64, 16), dim3(32, 8), 0, stream>>>(
            mlp_w1 + (size_t)i * 512 * 2048, wt_m1 + (size_t)i * 2048 * 512, 512, 2048, 512);
        tr_k<<<dim3(16, 64), dim3(32, 8), 0, stream>>>(
            mlp_w2 + (size_t)i * 2048 * 512, wt_m2 + (size_t)i * 512 * 2048, 2048, 512, 2048);
    }
    tr_k<<<dim3(16, 192), dim3(32, 8), 0, stream>>>(cls_w1, wt_c1, 6144, 512, 6144);
    tr_k<<<dim3(4, 16),  dim3(32, 8), 0, stream>>>(cls_w2, wt_c2, 512, 128, 512);

    // ---- pipeline per chunk of CH batches (M patch rows) ----
    for (int c = 0; c < nch; c++) {
        const float* xc = x + (size_t)c * CH * 480;
        factors_k<<<(CH + 63) / 64, 64, 0, stream>>>(xc, raw, stats, CH);
        featnorm_k<<<(M * 96) / 256, 256, 0, stream>>>(raw, stats, in_w, in_b, feats);
        gemm_f16<<<dim3(4, M / 128), 256, 0, stream>>>(
            feats, wt_pe, pe_b, nullptr, h32, nullptr, M, 512, 96, FLAG_W32);

        for (int i = 0; i < 4; i++) {
            ln_rows<<<M / 4, 256, 0, stream>>>(h32, ln1_w + i * 512, ln1_b + i * 512, abuf);
            gemm_f16<<<dim3(12, M / 128), 256, 0, stream>>>(
                abuf, wt_qkv + (size_t)i * 1536 * 512, qkv_b + i * 1536,
                nullptr, nullptr, bbuf, M, 1536, 512, FLAG_W16);
            attn_k<<<CH * 8, 64, 0, stream>>>(bbuf, abuf);
            gemm_f16<<<dim3(4, M / 128), 256, 0, stream>>>(
                abuf, wt_out + (size_t)i * 512 * 512, out_b + i * 512,
                h32, h32, nullptr, M, 512, 512, FLAG_RES | FLAG_W32);
            ln_rows<<<M / 4, 256, 0, stream>>>(h32, ln2_w + i * 512, ln2_b + i * 512, abuf);
            gemm_f16<<<dim3(16, M / 128), 256, 0, stream>>>(
                abuf, wt_m1 + (size_t)i * 2048 * 512, mlp_b1 + i * 2048,
                nullptr, nullptr, bbuf, M, 2048, 512, FLAG_W16 | FLAG_GELU);
            const int fl = FLAG_RES | FLAG_W32 | (i == 3 ? FLAG_W16 : 0);
            gemm_f16<<<dim3(4, M / 128), 256, 0, stream>>>(
                bbuf, wt_m2 + (size_t)i * 512 * 2048, mlp_b2 + i * 512,
                h32, h32, abuf, M, 512, 2048, fl);
        }

        // classifier: abuf viewed as (CH, 6144) f16
        gemm_f16<<<dim3(4, CH / 128), 256, 0, stream>>>(
            abuf, wt_c1, cls_b1, nullptr, nullptr, f1, CH, 512, 6144, FLAG_W16 | FLAG_GELU);
        gemm_f16<<<dim3(1, CH / 128), 256, 0, stream>>>(
            f1, wt_c2, cls_b2, nullptr, nullptr, f2, CH, 128, 512, FLAG_W16 | FLAG_GELU);
        cls3_k<<<(CH + 255) / 256, 256, 0, stream>>>(
            f2, cls_w3, cls_b3, (float*)d_out + (size_t)c * CH * 3, CH);
    }
}

// Round 8
// 3369.233 us; speedup vs baseline: 8.5681x; 1.4275x over previous
//
#include <hip/hip_runtime.h>
#include <cstdint>
#include <cstddef>

typedef _Float16 half8 __attribute__((ext_vector_type(8)));
typedef float floatx4 __attribute__((ext_vector_type(4)));

#define FLAG_RES  1
#define FLAG_GELU 2
#define FLAG_W32  4
#define FLAG_W16  8
#define FLAG_PART 16

__device__ __forceinline__ float gelu_exact(float x) {
    return 0.5f * x * (1.0f + erff(x * 0.70710678118654752f));
}

// ---------------------------------------------------------------------------
// GEMM: C(MxN) = A(MxK f16 rm) @ Bt(NxK f16 rm)^T + bias(fp32)
// 128x128 tile, BK=32, 256 thr (2x2 waves of 64x64). K-loop restructured:
// register prefetch + LDS ping-pong, ONE barrier per iteration (prefetch for
// tile k+1 issues after the barrier, overlaps frag-read+MFMA of tile k).
// blockIdx.z = split-K slice of length klen (klen%32==0). With FLAG_PART the
// raw fp32 partial goes to out32 + z*M*N (no bias/act/res).
// ---------------------------------------------------------------------------
__global__ __launch_bounds__(256, 2) void gemm_f16(
    const _Float16* __restrict__ A, const _Float16* __restrict__ Bt,
    const float* __restrict__ bias, const float* __restrict__ resid,
    float* __restrict__ out32, _Float16* __restrict__ out16,
    int M, int N, int K, int klen, int flags)
{
    __shared__ _Float16 As[2][128 * 32];
    __shared__ _Float16 Bs[2][128 * 32];
    const int tid = threadIdx.x;
    const int wid = tid >> 6;
    const int lane = tid & 63;
    const int bm = blockIdx.y * 128;
    const int bn = blockIdx.x * 128;
    const int wr = wid >> 1, wc = wid & 1;
    const int lane15 = lane & 15, quad = lane >> 4;
    const int kb = blockIdx.z * klen;

    floatx4 acc[4][4];
#pragma unroll
    for (int i = 0; i < 4; i++)
#pragma unroll
        for (int j = 0; j < 4; j++)
            acc[i][j] = floatx4{0.f, 0.f, 0.f, 0.f};

    // staging map (per wave, 32 rows of A and Bt): lane l -> row l/4, 16B chunk l%4
    const int r4 = lane >> 2;
    const int c8 = (lane & 3) << 3;
    const _Float16* Ap = A + ((size_t)bm + wid * 32 + r4) * K + kb + c8;
    const _Float16* Bp = Bt + ((size_t)bn + wid * 32 + r4) * K + kb + c8;
    const size_t row16 = (size_t)16 * K;
    const int lw = wid * 1024 + lane * 8;   // LDS write offset in halfs

    // prefetch tile 0 into registers
    int4 ra0 = *(const int4*)(Ap);
    int4 ra1 = *(const int4*)(Ap + row16);
    int4 rb0 = *(const int4*)(Bp);
    int4 rb1 = *(const int4*)(Bp + row16);

    const int nk = klen >> 5;
    for (int ik = 0; ik < nk; ik++) {
        _Float16* a_ = &As[ik & 1][0];
        _Float16* b_ = &Bs[ik & 1][0];
        *(int4*)(a_ + lw) = ra0;
        *(int4*)(a_ + lw + 512) = ra1;
        *(int4*)(b_ + lw) = rb0;
        *(int4*)(b_ + lw + 512) = rb1;
        __syncthreads();
        if (ik + 1 < nk) {                     // issue next-tile loads NOW;
            const int ko = (ik + 1) << 5;      // consumed at next ds_write
            ra0 = *(const int4*)(Ap + ko);
            ra1 = *(const int4*)(Ap + row16 + ko);
            rb0 = *(const int4*)(Bp + ko);
            rb1 = *(const int4*)(Bp + row16 + ko);
        }
        half8 af[4], bf[4];
#pragma unroll
        for (int mi = 0; mi < 4; mi++)
            af[mi] = *(const half8*)&a_[(wr * 64 + mi * 16 + lane15) * 32 + quad * 8];
#pragma unroll
        for (int ni = 0; ni < 4; ni++)
            bf[ni] = *(const half8*)&b_[(wc * 64 + ni * 16 + lane15) * 32 + quad * 8];
#pragma unroll
        for (int mi = 0; mi < 4; mi++)
#pragma unroll
            for (int ni = 0; ni < 4; ni++)
                acc[mi][ni] = __builtin_amdgcn_mfma_f32_16x16x32_f16(
                    af[mi], bf[ni], acc[mi][ni], 0, 0, 0);
        // no trailing barrier: iter ik+1 writes the other LDS buffer, and the
        // barrier at ik+1 orders those writes after everyone's reads of ik.
    }

    // epilogue: C/D layout col = lane&15, row = quad*4 + reg
    if (flags & FLAG_PART) {
        float* po = out32 + (size_t)blockIdx.z * ((size_t)M * N);
#pragma unroll
        for (int mi = 0; mi < 4; mi++) {
            const int gmb = bm + wr * 64 + mi * 16 + quad * 4;
#pragma unroll
            for (int ni = 0; ni < 4; ni++) {
                const int gn = bn + wc * 64 + ni * 16 + lane15;
#pragma unroll
                for (int r = 0; r < 4; r++)
                    po[(size_t)(gmb + r) * N + gn] = acc[mi][ni][r];
            }
        }
        return;
    }
#pragma unroll
    for (int mi = 0; mi < 4; mi++) {
        const int gmb = bm + wr * 64 + mi * 16 + quad * 4;
#pragma unroll
        for (int ni = 0; ni < 4; ni++) {
            const int gn = bn + wc * 64 + ni * 16 + lane15;
            const float bv = bias[gn];
#pragma unroll
            for (int r = 0; r < 4; r++) {
                float v = acc[mi][ni][r] + bv;
                if (flags & FLAG_GELU) v = gelu_exact(v);
                const size_t off = (size_t)(gmb + r) * N + gn;
                if (flags & FLAG_RES) v += resid[off];
                if (flags & FLAG_W32) out32[off] = v;
                if (flags & FLAG_W16) out16[off] = (_Float16)v;
            }
        }
    }
}

// ---------------------------------------------------------------------------
// Split-K reduce: out[i] = gelu(bias[i%N] + sum_z part[z*MN + i]) as f16.
// ---------------------------------------------------------------------------
__global__ __launch_bounds__(256) void skred_k(
    const float* __restrict__ part, const float* __restrict__ bias,
    _Float16* __restrict__ out, int MN, int N, int S)
{
    const int i = blockIdx.x * 256 + threadIdx.x;
    if (i >= MN) return;
    float s = bias[i % N];
    for (int z = 0; z < S; z++) s += part[(size_t)z * MN + i];
    out[i] = (_Float16)gelu_exact(s);
}

// ---------------------------------------------------------------------------
// Row LayerNorm over 512 cols: fp32 in, fp32 params, f16 out. One wave/row.
// ---------------------------------------------------------------------------
__global__ __launch_bounds__(256) void ln_rows(
    const float* __restrict__ x, const float* __restrict__ w,
    const float* __restrict__ b, _Float16* __restrict__ out)
{
    const int wid = threadIdx.x >> 6, lane = threadIdx.x & 63;
    const size_t row = (size_t)blockIdx.x * 4 + wid;
    const int c0 = lane * 8;
    const float* xr = x + row * 512 + c0;
    float4 v0 = *(const float4*)xr;
    float4 v1 = *(const float4*)(xr + 4);
    float xv[8] = {v0.x, v0.y, v0.z, v0.w, v1.x, v1.y, v1.z, v1.w};
    float s = 0.f, q = 0.f;
#pragma unroll
    for (int j = 0; j < 8; j++) { s += xv[j]; q += xv[j] * xv[j]; }
#pragma unroll
    for (int m = 32; m >= 1; m >>= 1) {
        s += __shfl_xor(s, m, 64);
        q += __shfl_xor(q, m, 64);
    }
    const float mean = s * (1.f / 512.f);
    const float rstd = rsqrtf(q * (1.f / 512.f) - mean * mean + 1e-5f);
    half8 o;
#pragma unroll
    for (int j = 0; j < 8; j++)
        o[j] = (_Float16)((xv[j] - mean) * rstd * w[c0 + j] + b[c0 + j]);
    *(half8*)&out[row * 512 + c0] = o;
}

// ---------------------------------------------------------------------------
// Attention: 4 (b,head) units per 256-thread block (one wave each).
// qkv rows (1536): [q|k|v], head offset hd*64. f16 in/out.
// ---------------------------------------------------------------------------
__global__ __launch_bounds__(256) void attn_k(
    const _Float16* __restrict__ qkv, _Float16* __restrict__ o)
{
    __shared__ float qs[4][12][65], ks[4][12][65], vs[4][12][65];
    __shared__ float att[4][12][16];
    const int wid = threadIdx.x >> 6, lane = threadIdx.x & 63;
    const int unit = blockIdx.x * 4 + wid;
    const int b = unit >> 3, hd = unit & 7;
    const _Float16* base = qkv + (size_t)b * (12 * 1536) + hd * 64 + lane;
#pragma unroll
    for (int r = 0; r < 12; r++) {
        qs[wid][r][lane] = (float)base[r * 1536];
        ks[wid][r][lane] = (float)base[r * 1536 + 512];
        vs[wid][r][lane] = (float)base[r * 1536 + 1024];
    }
    __syncthreads();
#pragma unroll
    for (int i = 0; i < 3; i++) {
        const int p = lane + i * 64;
        if (p < 144) {
            const int qi = p / 12, kj = p - qi * 12;
            float d = 0.f;
            for (int e = 0; e < 64; e++) d += qs[wid][qi][e] * ks[wid][kj][e];
            att[wid][qi][kj] = d * 0.125f;   // 1/sqrt(64)
        }
    }
    __syncthreads();
    if (lane < 12) {
        float mx = att[wid][lane][0];
#pragma unroll
        for (int j = 1; j < 12; j++) mx = fmaxf(mx, att[wid][lane][j]);
        float ev[12], ssum = 0.f;
#pragma unroll
        for (int j = 0; j < 12; j++) { ev[j] = expf(att[wid][lane][j] - mx); ssum += ev[j]; }
        const float inv = 1.f / ssum;
#pragma unroll
        for (int j = 0; j < 12; j++) att[wid][lane][j] = ev[j] * inv;
    }
    __syncthreads();
    _Float16* ob = o + (size_t)b * (12 * 512) + hd * 64 + lane;
#pragma unroll
    for (int qi = 0; qi < 12; qi++) {
        float s = 0.f;
#pragma unroll
        for (int j = 0; j < 12; j++) s += att[wid][qi][j] * vs[wid][j][lane];
        ob[qi * 512] = (_Float16)s;
    }
}

// ---------------------------------------------------------------------------
// Factors: one thread per batch row; serial T=96 scan. CH batches.
// ---------------------------------------------------------------------------
__global__ __launch_bounds__(64) void factors_k(
    const float* __restrict__ x, float* __restrict__ raw, float* __restrict__ stats,
    int CH)
{
    const int tid = threadIdx.x;
    const int b = blockIdx.x * 64 + tid;
    if (b >= CH) return;
    __shared__ float cl[96][64];
    __shared__ float vl[96][64];
    const float* xb = x + (size_t)b * 480;
    for (int t = 0; t < 96; t++) {
        cl[t][tid] = xb[t * 5 + 3];
        vl[t][tid] = xb[t * 5 + 4];
    }
    float e12 = cl[0][tid], e26 = e12;
    float ag = 0.f, al = 0.f;
    float s1c = 0.f, s2c = 0.f, s1v = 0.f;
    float sum[11], ssq[11];
#pragma unroll
    for (int f = 0; f < 11; f++) { sum[f] = 0.f; ssq[f] = 0.f; }
    const float a12 = 2.f / 13.f, a26 = 2.f / 27.f, a14 = 1.f / 14.f;
    for (int t = 0; t < 96; t++) {
        const float c = cl[t][tid];
        const float vraw = vl[t][tid];
        const float sv = vraw > 0.f ? vraw : 1.f;
        if (t > 0) {
            e12 = a12 * c + (1.f - a12) * e12;
            e26 = a26 * c + (1.f - a26) * e26;
        }
        const float macd = e12 - e26;
        const float cprev = t > 0 ? cl[t - 1][tid] : 0.f;
        const float delta = t > 0 ? c - cprev : 0.f;
        const float gain = fmaxf(delta, 0.f);
        const float loss = fmaxf(-delta, 0.f);
        if (t > 0) {
            ag = a14 * gain + (1.f - a14) * ag;
            al = a14 * loss + (1.f - a14) * al;
        }
        const float rs = ag / (al + 1e-10f);
        const float rsi = (100.f - 100.f / (1.f + rs)) * 0.01f;
        s1c += c; s2c += c * c; s1v += sv;
        if (t >= 20) {
            const float co = cl[t - 20][tid];
            const float vo = vl[t - 20][tid];
            const float svo = vo > 0.f ? vo : 1.f;
            s1c -= co; s2c -= co * co; s1v -= svo;
        }
        float bb = 0.f, vmr = 1.f;
        if (t >= 19) {
            const float mean = s1c * 0.05f;
            const float sq = s2c * 0.05f;
            const float sd = sqrtf(fmaxf(sq - mean * mean, 0.f));
            bb = 4.f * sd / (mean + 1e-8f);
            vmr = sv / (s1v * 0.05f + 1e-8f);
        }
        float lr = 0.f, lv = 0.f;
        if (t > 0) {
            lr = logf(fmaxf(c, 1e-8f) / fmaxf(cprev, 1e-8f));
            const float vprev = vl[t - 1][tid];
            const float svp = vprev > 0.f ? vprev : 1.f;
            lv = logf(sv / (svp + 1e-8f));
        }
        float fv[11];
        fv[0] = xb[t * 5 + 0];
        fv[1] = xb[t * 5 + 1];
        fv[2] = xb[t * 5 + 2];
        fv[3] = c;
        fv[4] = vraw;
        fv[5] = isfinite(macd) ? macd : 0.f;
        fv[6] = isfinite(rsi) ? rsi : 0.f;
        fv[7] = isfinite(bb) ? bb : 0.f;
        fv[8] = isfinite(lr) ? lr : 0.f;
        fv[9] = isfinite(lv) ? lv : 0.f;
        fv[10] = isfinite(vmr) ? vmr : 0.f;
        float* rp = raw + ((size_t)b * 96 + t) * 11;
#pragma unroll
        for (int f = 0; f < 11; f++) {
            rp[f] = fv[f];
            sum[f] += fv[f];
            ssq[f] += fv[f] * fv[f];
        }
    }
#pragma unroll
    for (int f = 0; f < 11; f++) {
        const float m = sum[f] * (1.f / 96.f);
        const float var = ssq[f] * (1.f / 96.f) - m * m;
        stats[(b * 11 + f) * 2] = m;
        stats[(b * 11 + f) * 2 + 1] = rsqrtf(var + 1e-5f);
    }
}

// ---------------------------------------------------------------------------
// Normalize feats -> (CH*12, 96) f16 patch rows (cols 88..95 zero pad).
// ---------------------------------------------------------------------------
__global__ __launch_bounds__(256) void featnorm_k(
    const float* __restrict__ raw, const float* __restrict__ stats,
    const float* __restrict__ in_w, const float* __restrict__ in_b,
    _Float16* __restrict__ out)
{
    const int idx = blockIdx.x * 256 + threadIdx.x;
    const int row = idx / 96;
    const int col = idx - row * 96;
    float val = 0.f;
    if (col < 88) {
        const int bq = row / 12;
        const int p = row - bq * 12;
        const int tsub = col / 11;
        const int f = col - tsub * 11;
        const int t = p * 8 + tsub;
        const float fvv = raw[((size_t)bq * 96 + t) * 11 + f];
        const float m = stats[(bq * 11 + f) * 2];
        const float r = stats[(bq * 11 + f) * 2 + 1];
        val = (fvv - m) * r * in_w[f] + in_b[f];
    }
    out[idx] = (_Float16)val;
}

// ---------------------------------------------------------------------------
// Tiled transpose + cast: W (K x N) fp32 -> Wt (N x Kpad) f16, zero-pad.
// ---------------------------------------------------------------------------
__global__ __launch_bounds__(256) void tr_k(
    const float* __restrict__ W, _Float16* __restrict__ Wt,
    int K, int N, int Kpad)
{
    __shared__ _Float16 t[32][33];
    const int n0 = blockIdx.x * 32, k0 = blockIdx.y * 32;
#pragma unroll
    for (int j = 0; j < 4; j++) {
        const int k = k0 + threadIdx.y + j * 8;
        t[threadIdx.y + j * 8][threadIdx.x] =
            (k < K) ? (_Float16)W[(size_t)k * N + n0 + threadIdx.x] : (_Float16)0.f;
    }
    __syncthreads();
#pragma unroll
    for (int j = 0; j < 4; j++) {
        const int n = n0 + threadIdx.y + j * 8;
        Wt[(size_t)n * Kpad + k0 + threadIdx.x] = t[threadIdx.x][threadIdx.y + j * 8];
    }
}

// ---------------------------------------------------------------------------
// Final tiny GEMM: (CH x 128 f16) @ (128 x 3) + bias -> fp32 out.
// ---------------------------------------------------------------------------
__global__ __launch_bounds__(256) void cls3_k(
    const _Float16* __restrict__ f2, const float* __restrict__ w3,
    const float* __restrict__ b3, float* __restrict__ out, int CH)
{
    const int bq = blockIdx.x * 256 + threadIdx.x;
    if (bq >= CH) return;
    float a0 = b3[0], a1 = b3[1], a2 = b3[2];
    const _Float16* fr = f2 + (size_t)bq * 128;
    for (int k = 0; k < 128; k++) {
        const float xv = (float)fr[k];
        a0 += xv * w3[k * 3];
        a1 += xv * w3[k * 3 + 1];
        a2 += xv * w3[k * 3 + 2];
    }
    out[bq * 3] = a0;
    out[bq * 3 + 1] = a1;
    out[bq * 3 + 2] = a2;
}

// ---------------------------------------------------------------------------
extern "C" void kernel_launch(void* const* d_in, const int* in_sizes, int n_in,
                              void* d_out, int out_size, void* d_ws, size_t ws_size,
                              hipStream_t stream)
{
    static const int EXP[23] = {1966080, 11, 11, 45056, 512, 2048, 2048,
        3145728, 6144, 1048576, 2048, 2048, 2048, 4194304, 8192, 4194304, 2048,
        3145728, 512, 65536, 128, 384, 3};
    static const int S2D[23] = {18, 20, 22, 17, 19, 21, 2, 1, 6, 5, 12, 11,
        14, 16, 13, 15, 10, 9, 4, 3, 8, 7, 0};
    const void* in[23];
    if (n_in != 23 || out_size != 12288) return;
    bool ok = true;
    for (int i = 0; i < 23; i++) ok = ok && (in_sizes[i] == EXP[i]);
    if (ok) {
        for (int i = 0; i < 23; i++) in[i] = d_in[i];
    } else {
        bool ok2 = true;
        for (int s = 0; s < 23; s++) ok2 = ok2 && (in_sizes[s] == EXP[S2D[s]]);
        if (!ok2) return;
        for (int s = 0; s < 23; s++) in[S2D[s]] = d_in[s];
    }
    const float* x      = (const float*)in[0];
    const float* in_w   = (const float*)in[1];
    const float* in_b   = (const float*)in[2];
    const float* pe_w   = (const float*)in[3];
    const float* pe_b   = (const float*)in[4];
    const float* ln1_w  = (const float*)in[5];
    const float* ln1_b  = (const float*)in[6];
    const float* qkv_w  = (const float*)in[7];
    const float* qkv_b  = (const float*)in[8];
    const float* out_w  = (const float*)in[9];
    const float* out_b  = (const float*)in[10];
    const float* ln2_w  = (const float*)in[11];
    const float* ln2_b  = (const float*)in[12];
    const float* mlp_w1 = (const float*)in[13];
    const float* mlp_b1 = (const float*)in[14];
    const float* mlp_w2 = (const float*)in[15];
    const float* mlp_b2 = (const float*)in[16];
    const float* cls_w1 = (const float*)in[17];
    const float* cls_b1 = (const float*)in[18];
    const float* cls_w2 = (const float*)in[19];
    const float* cls_b2 = (const float*)in[20];
    const float* cls_w3 = (const float*)in[21];
    const float* cls_b3 = (const float*)in[22];

    // ---- f16 weight arena (~31.7 MB) ----
    char* ws = (char*)d_ws;
    size_t off = 0;
    _Float16* wt_pe  = (_Float16*)(ws + off); off += (size_t)512 * 96 * 2;
    _Float16* wt_qkv = (_Float16*)(ws + off); off += (size_t)4 * 1536 * 512 * 2;
    _Float16* wt_out = (_Float16*)(ws + off); off += (size_t)4 * 512 * 512 * 2;
    _Float16* wt_m1  = (_Float16*)(ws + off); off += (size_t)4 * 2048 * 512 * 2;
    _Float16* wt_m2  = (_Float16*)(ws + off); off += (size_t)4 * 512 * 2048 * 2;
    _Float16* wt_c1  = (_Float16*)(ws + off); off += (size_t)512 * 6144 * 2;
    _Float16* wt_c2  = (_Float16*)(ws + off); off += (size_t)128 * 512 * 2;
    const size_t wbytes = off;

    // adaptive chunk: per-batch bytes = h32 24576 + abuf 12288 + bbuf 49152
    //                                  + raw 4224 + stats 88 = 90328
    const size_t per = 90328 + 64;
    int CH = 4096;                             // single-pass if ws allows
    while (CH > 128 && wbytes + (size_t)CH * per > ws_size) CH >>= 1;
    const int nch = 4096 / CH;
    const int M = CH * 12;

    float*    h32  = (float*)(ws + off);    off += (size_t)M * 512 * 4;
    _Float16* abuf = (_Float16*)(ws + off); off += (size_t)M * 512 * 2;
    _Float16* bbuf = (_Float16*)(ws + off); off += (size_t)M * 2048 * 2;
    float*    raw  = (float*)(ws + off);    off += (size_t)CH * 96 * 11 * 4;
    float*    stats= (float*)(ws + off);    off += (size_t)CH * 11 * 2 * 4;

    _Float16* feats = bbuf;                 // dead after pe GEMM
    _Float16* f1 = (_Float16*)raw;          // classifier temps (raw dead then)
    _Float16* f2 = f1 + (size_t)CH * 512;
    float* part1 = (float*)bbuf;                          // 8*CH*512 fp32
    float* part2 = part1 + (size_t)8 * CH * 512;          // 4*CH*128 fp32

    // ---- weight prep: fp32 (K,N) -> f16 (N,Kpad) transposed (once) ----
    tr_k<<<dim3(16, 3),  dim3(32, 8), 0, stream>>>(pe_w, wt_pe, 88, 512, 96);
    for (int i = 0; i < 4; i++) {
        tr_k<<<dim3(48, 16), dim3(32, 8), 0, stream>>>(
            qkv_w + (size_t)i * 512 * 1536, wt_qkv + (size_t)i * 1536 * 512, 512, 1536, 512);
        tr_k<<<dim3(16, 16), dim3(32, 8), 0, stream>>>(
            out_w + (size_t)i * 512 * 512, wt_out + (size_t)i * 512 * 512, 512, 512, 512);
        tr_k<<<dim3(64, 16), dim3(32, 8), 0, stream>>>(
            mlp_w1 + (size_t)i * 512 * 2048, wt_m1 + (size_t)i * 2048 * 512, 512, 2048, 512);
        tr_k<<<dim3(16, 64), dim3(32, 8), 0, stream>>>(
            mlp_w2 + (size_t)i * 2048 * 512, wt_m2 + (size_t)i * 512 * 2048, 2048, 512, 2048);
    }
    tr_k<<<dim3(16, 192), dim3(32, 8), 0, stream>>>(cls_w1, wt_c1, 6144, 512, 6144);
    tr_k<<<dim3(4, 16),  dim3(32, 8), 0, stream>>>(cls_w2, wt_c2, 512, 128, 512);

    for (int c = 0; c < nch; c++) {
        const float* xc = x + (size_t)c * CH * 480;
        factors_k<<<(CH + 63) / 64, 64, 0, stream>>>(xc, raw, stats, CH);
        featnorm_k<<<(M * 96) / 256, 256, 0, stream>>>(raw, stats, in_w, in_b, feats);
        gemm_f16<<<dim3(4, M / 128), 256, 0, stream>>>(
            feats, wt_pe, pe_b, nullptr, h32, nullptr, M, 512, 96, 96, FLAG_W32);

        for (int i = 0; i < 4; i++) {
            ln_rows<<<M / 4, 256, 0, stream>>>(h32, ln1_w + i * 512, ln1_b + i * 512, abuf);
            gemm_f16<<<dim3(12, M / 128), 256, 0, stream>>>(
                abuf, wt_qkv + (size_t)i * 1536 * 512, qkv_b + i * 1536,
                nullptr, nullptr, bbuf, M, 1536, 512, 512, FLAG_W16);
            attn_k<<<CH * 2, 256, 0, stream>>>(bbuf, abuf);
            gemm_f16<<<dim3(4, M / 128), 256, 0, stream>>>(
                abuf, wt_out + (size_t)i * 512 * 512, out_b + i * 512,
                h32, h32, nullptr, M, 512, 512, 512, FLAG_RES | FLAG_W32);
            ln_rows<<<M / 4, 256, 0, stream>>>(h32, ln2_w + i * 512, ln2_b + i * 512, abuf);
            gemm_f16<<<dim3(16, M / 128), 256, 0, stream>>>(
                abuf, wt_m1 + (size_t)i * 2048 * 512, mlp_b1 + i * 2048,
                nullptr, nullptr, bbuf, M, 2048, 512, 512, FLAG_W16 | FLAG_GELU);
            const int fl = FLAG_RES | FLAG_W32 | (i == 3 ? FLAG_W16 : 0);
            gemm_f16<<<dim3(4, M / 128), 256, 0, stream>>>(
                bbuf, wt_m2 + (size_t)i * 512 * 2048, mlp_b2 + i * 512,
                h32, h32, abuf, M, 512, 2048, 2048, fl);
        }

        // classifier: abuf viewed as (CH, 6144) f16; split-K via fp32 partials
        gemm_f16<<<dim3(4, CH / 128, 8), 256, 0, stream>>>(
            abuf, wt_c1, nullptr, nullptr, part1, nullptr, CH, 512, 6144, 768, FLAG_PART);
        skred_k<<<(CH * 512 + 255) / 256, 256, 0, stream>>>(
            part1, cls_b1, f1, CH * 512, 512, 8);
        gemm_f16<<<dim3(1, CH / 128, 4), 256, 0, stream>>>(
            f1, wt_c2, nullptr, nullptr, part2, nullptr, CH, 128, 512, 128, FLAG_PART);
        skred_k<<<(CH * 128 + 255) / 256, 256, 0, stream>>>(
            part2, cls_b2, f2, CH * 128, 128, 4);
        cls3_k<<<(CH + 255) / 256, 256, 0, stream>>>(
            f2, cls_w3, cls_b3, (float*)d_out + (size_t)c * CH * 3, CH);
    }
}